// Round 1
// baseline (557.958 us; speedup 1.0000x reference)
//
#include <hip/hip_runtime.h>
#include <hip/hip_bf16.h>

typedef __bf16 bf16x8 __attribute__((ext_vector_type(8)));
typedef __bf16 bf16x4 __attribute__((ext_vector_type(4)));
typedef float  f32x4  __attribute__((ext_vector_type(4)));

#define KNB  9
#define BM   64
#define ROWB 768   // bytes per LDS row: 384 bf16

__device__ __forceinline__ bf16x4 cvt4(f32x4 a) {
  bf16x4 t;
  t[0] = (__bf16)a[0]; t[1] = (__bf16)a[1];
  t[2] = (__bf16)a[2]; t[3] = (__bf16)a[3];
  return t;
}

// C(64x128) = [g0|g1|g2](64x384) @ W(384x128) + bias, fused with the gather.
__global__ __launch_bounds__(256, 2)
void sfc_fused(const float* __restrict__ x,
               const float* __restrict__ w0,
               const float* __restrict__ w1,
               const float* __restrict__ w2,
               const float* __restrict__ bias,
               const int*   __restrict__ fn,
               float* __restrict__ out,
               int n_real)
{
  __shared__ char Gs[BM * ROWB];          // 48 KiB, XOR-swizzled bf16 G-tile
  const int tid = (int)threadIdx.x;
  const int l   = tid & 63;
  const int w   = tid >> 6;               // wave id 0..3
  const int m0  = (int)blockIdx.x * BM;

  // ---------------- B-operand preload: 12 k-steps x 2 n-tiles per wave ----------
  // B[k][o] with k = g*128 + c, fragment: lane l -> col o0+nt*16+(l&15),
  // k = ks*32 + (l>>4)*8 + j  (8 consecutive c -> contiguous fp32 load).
  const int o0 = w * 32;
  bf16x8 bfr[12][2];
  #pragma unroll
  for (int ks = 0; ks < 12; ++ks) {
    const int k = ks * 32 + ((l >> 4) << 3);
    const int g = k >> 7;
    const int c = k & 127;
    const float* wsel = (g == 0) ? w0 : ((g == 1) ? w1 : w2);
    #pragma unroll
    for (int nt = 0; nt < 2; ++nt) {
      const int o = o0 + nt * 16 + (l & 15);
      const float* wp = wsel + o * 128 + c;
      f32x4 lo = *(const f32x4*)(wp);
      f32x4 hi = *(const f32x4*)(wp + 4);
      bf16x8 t;
      t[0]=(__bf16)lo[0]; t[1]=(__bf16)lo[1]; t[2]=(__bf16)lo[2]; t[3]=(__bf16)lo[3];
      t[4]=(__bf16)hi[0]; t[5]=(__bf16)hi[1]; t[6]=(__bf16)hi[2]; t[7]=(__bf16)hi[3];
      bfr[ks][nt] = t;
    }
  }

  // ---------------- gather + symmetric fold into LDS ----------------------------
  // Half-wave per face: 32 lanes x float4 = one full 512B x-row per request.
  const int half = l >> 5;
  const int lc   = l & 31;
  #pragma unroll 2
  for (int p = 0; p < 8; ++p) {
    const int f    = w * 16 + p * 2 + half;          // row within block
    const int base = (m0 + f) * KNB;
    f32x4 a0 = {0.f,0.f,0.f,0.f}, a1 = a0, a2 = a0;
    #pragma unroll
    for (int k = 0; k < KNB; ++k) {
      const int nb = fn[base + k];
      f32x4 v = {0.f,0.f,0.f,0.f};
      if (nb < n_real)                               // idx==n_real is the zero pad row
        v = *(const f32x4*)(x + ((size_t)nb << 7) + (lc << 2));
      if (k == 0)      a0 = v;
      else if (k & 1)  a1 += v;                      // slots 1,3,5,7 -> w1
      else             a2 += v;                      // slots 2,4,6,8 -> w2
    }
    char* rb = Gs + f * ROWB;
    const unsigned swz = (unsigned)((f & 7) << 4);   // T2 XOR swizzle (bits 4-6)
    *(bf16x4*)(rb + (((unsigned)(lc << 3)        ) ^ swz)) = cvt4(a0);
    *(bf16x4*)(rb + (((unsigned)(lc << 3) +  256u) ^ swz)) = cvt4(a1);
    *(bf16x4*)(rb + (((unsigned)(lc << 3) +  512u) ^ swz)) = cvt4(a2);
  }
  __syncthreads();

  // ---------------- MFMA: per wave C(64x32) = G(64x384) x W(384x32) -------------
  f32x4 acc[4][2] = {};
  #pragma unroll
  for (int ks = 0; ks < 12; ++ks) {
    bf16x8 af[4];
    #pragma unroll
    for (int mt = 0; mt < 4; ++mt) {
      const unsigned row = (unsigned)(mt * 16 + (l & 15));
      unsigned off = row * ROWB + (unsigned)((ks * 32 + ((l >> 4) << 3)) << 1);
      off ^= (unsigned)((l & 7) << 4);               // row&7 == l&7 here
      af[mt] = *(const bf16x8*)(Gs + off);
    }
    #pragma unroll
    for (int mt = 0; mt < 4; ++mt)
      #pragma unroll
      for (int nt = 0; nt < 2; ++nt)
        acc[mt][nt] = __builtin_amdgcn_mfma_f32_16x16x32_bf16(
            af[mt], bfr[ks][nt], acc[mt][nt], 0, 0, 0);
  }

  // ---------------- epilogue: + bias, fp32 store ---------------------------------
  const float bv0 = bias[o0 +      (l & 15)];
  const float bv1 = bias[o0 + 16 + (l & 15)];
  #pragma unroll
  for (int mt = 0; mt < 4; ++mt) {
    #pragma unroll
    for (int r = 0; r < 4; ++r) {
      const int m = m0 + mt * 16 + ((l >> 4) << 2) + r;   // D: row=(lane>>4)*4+reg
      float* orow = out + (size_t)m * 128 + o0;
      orow[(l & 15)]      = acc[mt][0][r] + bv0;          // D: col=lane&15
      orow[16 + (l & 15)] = acc[mt][1][r] + bv1;
    }
  }
}

extern "C" void kernel_launch(void* const* d_in, const int* in_sizes, int n_in,
                              void* d_out, int out_size, void* d_ws, size_t ws_size,
                              hipStream_t stream) {
  const float* x    = (const float*)d_in[0];
  const float* w0   = (const float*)d_in[1];
  const float* w1   = (const float*)d_in[2];
  const float* w2   = (const float*)d_in[3];
  const float* bias = (const float*)d_in[4];
  const int*   fn   = (const int*)d_in[5];
  float* out = (float*)d_out;

  const int n_real = in_sizes[0] / 128;   // 262144
  const int grid   = n_real / BM;         // 4096 blocks, 256 thr (4 waves)
  sfc_fused<<<grid, 256, 0, stream>>>(x, w0, w1, w2, bias, fn, out, n_real);
}

// Round 4
// 397.970 us; speedup vs baseline: 1.4020x; 1.4020x over previous
//
#include <hip/hip_runtime.h>
#include <hip/hip_bf16.h>

typedef __bf16 bf16x8 __attribute__((ext_vector_type(8)));
typedef __bf16 bf16x4 __attribute__((ext_vector_type(4)));
typedef float  f32x4  __attribute__((ext_vector_type(4)));

#define KNB  9
#define BM   64
#define ROWB 768   // bytes per LDS row: 384 bf16 ([g0|g1|g2], 128 cols each)

// ---------------- x fp32 -> bf16 table (d_ws) ----------------------------------
__global__ __launch_bounds__(256) void cvt_bf16(const float* __restrict__ x,
                                                __bf16* __restrict__ t) {
  const size_t i = ((size_t)blockIdx.x * 256 + threadIdx.x) * 8;
  f32x4 a = *(const f32x4*)(x + i);
  f32x4 b = *(const f32x4*)(x + i + 4);
  bf16x8 o;
  o[0]=(__bf16)a[0]; o[1]=(__bf16)a[1]; o[2]=(__bf16)a[2]; o[3]=(__bf16)a[3];
  o[4]=(__bf16)b[0]; o[5]=(__bf16)b[1]; o[6]=(__bf16)b[2]; o[7]=(__bf16)b[3];
  *(bf16x8*)(t + i) = o;
}

// ---------------- fused gather + symmetric fold + MFMA -------------------------
// BF16TAB=1: gather bf16 rows (256B) from table; else fp32 rows (512B) from x.
template<bool BF16TAB>
__global__ __launch_bounds__(256, 3)
void sfc_main(const void* __restrict__ xtab,
              const float* __restrict__ w0,
              const float* __restrict__ w1,
              const float* __restrict__ w2,
              const float* __restrict__ bias,
              const int*   __restrict__ fn,
              float* __restrict__ out,
              int n_real)
{
  __shared__ char Gs[BM * ROWB];          // 48 KiB, XOR-swizzled bf16 G-tile
  const int tid = (int)threadIdx.x;
  const int l   = tid & 63;
  const int w   = tid >> 6;               // wave id 0..3
  const int m0  = (int)blockIdx.x * BM;
  const int g   = l >> 4;                 // 16-lane group 0..3 (4 faces/wave in flight)
  const int lc  = l & 15;

  // ---------- gather phase: wave covers faces w*16 .. w*16+15, 4 at a time ------
  #pragma unroll 2
  for (int p = 0; p < 4; ++p) {
    const int f    = w * 16 + p * 4 + g;
    const int base = (m0 + f) * KNB;
    int idx[KNB];
    #pragma unroll
    for (int k = 0; k < KNB; ++k) idx[k] = fn[base + k];

    char* rb = Gs + f * ROWB;
    const unsigned swz = (unsigned)((f & 7) << 4);   // XOR bits 4-6

    if constexpr (BF16TAB) {
      const __bf16* xt = (const __bf16*)xtab;
      bf16x8 v[KNB];
      #pragma unroll
      for (int k = 0; k < KNB; ++k) {
        bf16x8 z; 
        #pragma unroll
        for (int j = 0; j < 8; ++j) z[j] = (__bf16)0.f;
        v[k] = z;
        if (idx[k] < n_real)
          v[k] = *(const bf16x8*)(xt + ((size_t)idx[k] << 7) + (lc << 3));
      }
      float a1[8], a2[8];
      #pragma unroll
      for (int j = 0; j < 8; ++j) {
        a1[j] = (float)v[1][j] + (float)v[3][j] + (float)v[5][j] + (float)v[7][j];
        a2[j] = (float)v[2][j] + (float)v[4][j] + (float)v[6][j] + (float)v[8][j];
      }
      bf16x8 c1, c2;
      #pragma unroll
      for (int j = 0; j < 8; ++j) { c1[j] = (__bf16)a1[j]; c2[j] = (__bf16)a2[j]; }
      const unsigned o = (unsigned)(lc << 4);
      *(bf16x8*)(rb + ((o        ) ^ swz)) = v[0];
      *(bf16x8*)(rb + ((o + 256u ) ^ swz)) = c1;
      *(bf16x8*)(rb + ((o + 512u ) ^ swz)) = c2;
    } else {
      const float* x = (const float*)xtab;
      f32x4 a0[2], a1[2], a2[2];
      #pragma unroll
      for (int h = 0; h < 2; ++h) { a0[h] = {0,0,0,0}; a1[h] = a0[h]; a2[h] = a0[h]; }
      #pragma unroll
      for (int k = 0; k < KNB; ++k) {
        #pragma unroll
        for (int h = 0; h < 2; ++h) {
          f32x4 v = {0,0,0,0};
          if (idx[k] < n_real)
            v = *(const f32x4*)(x + ((size_t)idx[k] << 7) + h * 64 + (lc << 2));
          if (k == 0)      a0[h] = v;
          else if (k & 1)  a1[h] += v;
          else             a2[h] += v;
        }
      }
      #pragma unroll
      for (int h = 0; h < 2; ++h) {
        const unsigned o = (unsigned)(h * 128 + (lc << 3));
        bf16x4 b0, b1, b2;
        #pragma unroll
        for (int j = 0; j < 4; ++j) {
          b0[j]=(__bf16)a0[h][j]; b1[j]=(__bf16)a1[h][j]; b2[j]=(__bf16)a2[h][j];
        }
        *(bf16x4*)(rb + ((o        ) ^ swz)) = b0;
        *(bf16x4*)(rb + ((o + 256u ) ^ swz)) = b1;
        *(bf16x4*)(rb + ((o + 512u ) ^ swz)) = b2;
      }
    }
  }
  __syncthreads();

  // ---------- B-operand load after barrier (short live range) -------------------
  // B[k][o], k = g*128+c: lane -> col o0+nt*16+(l&15), k = ks*32+(l>>4)*8+j.
  const int o0 = w * 32;
  bf16x8 bfr[12][2];
  #pragma unroll
  for (int ks = 0; ks < 12; ++ks) {
    const int k = ks * 32 + ((l >> 4) << 3);
    const int gg = k >> 7;
    const int c  = k & 127;
    const float* wsel = (gg == 0) ? w0 : ((gg == 1) ? w1 : w2);
    #pragma unroll
    for (int nt = 0; nt < 2; ++nt) {
      const int o = o0 + nt * 16 + (l & 15);
      const float* wp = wsel + o * 128 + c;
      f32x4 lo = *(const f32x4*)(wp);
      f32x4 hi = *(const f32x4*)(wp + 4);
      bf16x8 t;
      t[0]=(__bf16)lo[0]; t[1]=(__bf16)lo[1]; t[2]=(__bf16)lo[2]; t[3]=(__bf16)lo[3];
      t[4]=(__bf16)hi[0]; t[5]=(__bf16)hi[1]; t[6]=(__bf16)hi[2]; t[7]=(__bf16)hi[3];
      bfr[ks][nt] = t;
    }
  }

  // ---------- MFMA: per wave C(64x32) = G(64x384) x W(384x32) -------------------
  f32x4 acc[4][2] = {};
  #pragma unroll
  for (int ks = 0; ks < 12; ++ks) {
    bf16x8 af[4];
    #pragma unroll
    for (int mt = 0; mt < 4; ++mt) {
      const unsigned row = (unsigned)(mt * 16 + (l & 15));
      unsigned off = row * ROWB + (unsigned)((ks * 32 + ((l >> 4) << 3)) << 1);
      off ^= (unsigned)((l & 7) << 4);               // row&7 == l&7 here
      af[mt] = *(const bf16x8*)(Gs + off);
    }
    #pragma unroll
    for (int mt = 0; mt < 4; ++mt)
      #pragma unroll
      for (int nt = 0; nt < 2; ++nt)
        acc[mt][nt] = __builtin_amdgcn_mfma_f32_16x16x32_bf16(
            af[mt], bfr[ks][nt], acc[mt][nt], 0, 0, 0);
  }

  // ---------- epilogue: + bias, fp32 store ---------------------------------------
  const float bv0 = bias[o0 +      (l & 15)];
  const float bv1 = bias[o0 + 16 + (l & 15)];
  #pragma unroll
  for (int mt = 0; mt < 4; ++mt) {
    #pragma unroll
    for (int r = 0; r < 4; ++r) {
      const int m = m0 + mt * 16 + ((l >> 4) << 2) + r;   // D: row=(lane>>4)*4+reg
      float* orow = out + (size_t)m * 128 + o0;
      orow[(l & 15)]      = acc[mt][0][r] + bv0;          // D: col=lane&15
      orow[16 + (l & 15)] = acc[mt][1][r] + bv1;
    }
  }
}

extern "C" void kernel_launch(void* const* d_in, const int* in_sizes, int n_in,
                              void* d_out, int out_size, void* d_ws, size_t ws_size,
                              hipStream_t stream) {
  const float* x    = (const float*)d_in[0];
  const float* w0   = (const float*)d_in[1];
  const float* w1   = (const float*)d_in[2];
  const float* w2   = (const float*)d_in[3];
  const float* bias = (const float*)d_in[4];
  const int*   fn   = (const int*)d_in[5];
  float* out = (float*)d_out;

  const int n_real = in_sizes[0] / 128;           // 262144
  const int grid   = n_real / BM;                 // 4096 blocks, 256 thr (4 waves)
  const size_t need = (size_t)n_real * 128 * sizeof(__bf16);   // 67 MB

  if (ws_size >= need) {
    __bf16* xtab = (__bf16*)d_ws;
    const int cgrid = (n_real * 128) / (256 * 8); // 16384
    cvt_bf16<<<cgrid, 256, 0, stream>>>(x, xtab);
    sfc_main<true><<<grid, 256, 0, stream>>>(xtab, w0, w1, w2, bias, fn, out, n_real);
  } else {
    sfc_main<false><<<grid, 256, 0, stream>>>(x, w0, w1, w2, bias, fn, out, n_real);
  }
}